// Round 11
// baseline (138.895 us; speedup 1.0000x reference)
//
#include <hip/hip_runtime.h>
#include <stdint.h>

#define VSZ 30000
#define TPS 2048      // trees per side
#define G3  384

// workspace layout (float offsets)
#define OFF_PROJ   0u          // 30000*128 bf16 = 1,920,000 floats
#define OFF_WCT    1920000u    // 128*128
#define OFF_WIHTF  1936384u    // 128*384
#define OFF_WIHTB  1985536u    // 128*384
#define OFF_SEQ    2034688u    // 2*2048*128
#define OFF_GI     2558976u    // 4*64*32*384
#define OFF_HFIN   5704704u    // 256*128
#define OFF_FRAG   5737472u    // 24576 uint4 = 98304 floats

using f32x4 = __attribute__((ext_vector_type(4))) float;
using s16x8 = __attribute__((ext_vector_type(8))) short;
union U8 { uint4 u; s16x8 s; };

__device__ __forceinline__ float sigm(float x) { return 1.0f / (1.0f + __expf(-x)); }
__device__ __forceinline__ float tanh_fast(float x) {
  float e = __expf(-2.0f * x);
  return 2.0f / (1.0f + e) - 1.0f;   // safe at both tails (no inf/inf)
}
__device__ __forceinline__ unsigned bf16_rn(float f) {
  unsigned u = __float_as_uint(f);
  return (u + 0x7FFFu + ((u >> 16) & 1u)) >> 16;   // round-to-nearest-even
}

// ---- K0: transpose three [R][128] -> [128][R] in one launch
__global__ __launch_bounds__(256) void k_transpose3(const float* __restrict__ w_c,
                                                    const float* __restrict__ wf,
                                                    const float* __restrict__ wb,
                                                    float* __restrict__ dwc,
                                                    float* __restrict__ dwf,
                                                    float* __restrict__ dwb) {
  __shared__ float tile[32][129];
  int b = blockIdx.x;
  const float* src; float* dst; int R, r0;
  if (b < 4)       { src = w_c; dst = dwc; R = 128; r0 = b * 32; }
  else if (b < 16) { src = wf;  dst = dwf; R = 384; r0 = (b - 4) * 32; }
  else             { src = wb;  dst = dwb; R = 384; r0 = (b - 16) * 32; }
  for (int idx = threadIdx.x; idx < 32 * 128; idx += 256) {
    int r = idx >> 7, c = idx & 127;
    tile[r][c] = src[(r0 + r) * 128 + c];
  }
  __syncthreads();
  for (int idx = threadIdx.x; idx < 32 * 128; idx += 256) {
    int k = idx >> 5, r = idx & 31;
    dst[k * R + r0 + r] = tile[r][k];
  }
}

// ---- K0b: pre-pack GRU weight MFMA A-fragments as bf16, one dwordx4/lane.
//      idx = ((((dir*8+w)*2+mat)*3+g)*4+t)*64 + l   (mat0=W_ih, mat1=W_hh)
__global__ __launch_bounds__(256) void k_pack(
    const float* __restrict__ w_ih_f, const float* __restrict__ w_ih_b,
    const float* __restrict__ w_hh_f, const float* __restrict__ w_hh_b,
    uint4* __restrict__ fragimg) {
  int idx = blockIdx.x * 256 + threadIdx.x;    // 0..24575
  int l = idx & 63;
  int t = (idx >> 6) & 3;
  int r = idx >> 8;
  int g = r % 3; r /= 3;
  int mat = r & 1; r >>= 1;
  int w = r & 7;
  int dir = r >> 3;
  const float* src = mat ? (dir ? w_hh_b : w_hh_f) : (dir ? w_ih_b : w_ih_f);
  int row = g * 128 + 16 * w + (l & 15);
  int ks  = t * 32 + (l >> 4) * 8;
  float4 f0 = *(const float4*)&src[row * 128 + ks];
  float4 f1 = *(const float4*)&src[row * 128 + ks + 4];
  uint4 u;
  u.x = bf16_rn(f0.x) | (bf16_rn(f0.y) << 16);
  u.y = bf16_rn(f0.z) | (bf16_rn(f0.w) << 16);
  u.z = bf16_rn(f1.x) | (bf16_rn(f1.y) << 16);
  u.w = bf16_rn(f1.z) | (bf16_rn(f1.w) << 16);
  fragimg[idx] = u;
}

// ---- K1: proj[v][eo] = b_c[eo] + sum_k emb[v][k] * w_c[eo][k]; output bf16
__global__ __launch_bounds__(256) void k_proj(const float* __restrict__ emb,
                                              const float* __restrict__ wcT,
                                              const float* __restrict__ b_c,
                                              unsigned short* __restrict__ projb) {
  __shared__ float wT[128 * 128];     // 64 KB, [k][eo]
  __shared__ float es[32][128];       // 16 KB
  int v0 = blockIdx.x * 32;
  for (int idx = threadIdx.x; idx < 128 * 32; idx += 256)
    ((float4*)wT)[idx] = ((const float4*)wcT)[idx];
  for (int idx = threadIdx.x; idx < 32 * 32; idx += 256) {
    int v = idx >> 5;
    float4 val = make_float4(0.f, 0.f, 0.f, 0.f);
    if (v0 + v < VSZ) val = ((const float4*)emb)[v0 * 32 + idx];
    ((float4*)es)[idx] = val;
  }
  __syncthreads();
  int tv = (threadIdx.x >> 5) << 2;   // v base (0..28)
  int te = (threadIdx.x & 31) << 2;   // eo base (0..124)
  float4 bc4 = *(const float4*)&b_c[te];
  float4 a0 = bc4, a1 = bc4, a2 = bc4, a3 = bc4;
#pragma unroll 4
  for (int kk = 0; kk < 128; ++kk) {
    float4 w4 = *(float4*)&wT[kk * 128 + te];
    float e0 = es[tv + 0][kk], e1 = es[tv + 1][kk];
    float e2 = es[tv + 2][kk], e3 = es[tv + 3][kk];
    a0.x = fmaf(e0, w4.x, a0.x); a0.y = fmaf(e0, w4.y, a0.y);
    a0.z = fmaf(e0, w4.z, a0.z); a0.w = fmaf(e0, w4.w, a0.w);
    a1.x = fmaf(e1, w4.x, a1.x); a1.y = fmaf(e1, w4.y, a1.y);
    a1.z = fmaf(e1, w4.z, a1.z); a1.w = fmaf(e1, w4.w, a1.w);
    a2.x = fmaf(e2, w4.x, a2.x); a2.y = fmaf(e2, w4.y, a2.y);
    a2.z = fmaf(e2, w4.z, a2.z); a2.w = fmaf(e2, w4.w, a2.w);
    a3.x = fmaf(e3, w4.x, a3.x); a3.y = fmaf(e3, w4.y, a3.y);
    a3.z = fmaf(e3, w4.z, a3.z); a3.w = fmaf(e3, w4.w, a3.w);
  }
#pragma unroll
  for (int i = 0; i < 4; ++i) {
    float4 a = (i == 0) ? a0 : (i == 1) ? a1 : (i == 2) ? a2 : a3;
    int v = v0 + tv + i;
    if (v < VSZ) {
      uint2 u;
      u.x = bf16_rn(a.x) | (bf16_rn(a.y) << 16);
      u.y = bf16_rn(a.z) | (bf16_rn(a.w) << 16);
      *(uint2*)&projb[(size_t)v * 128 + te] = u;
    }
  }
}

// ---- K2: per-tree subtree sums (heap), coord-wise max, ReLU -> seq[side][t][c]
__global__ __launch_bounds__(256) void k_tree(const int* __restrict__ tokens1,
                                              const int* __restrict__ tokens2,
                                              const unsigned short* __restrict__ projb,
                                              float* __restrict__ seq) {
  __shared__ int tok[2][64];
  int side = blockIdx.y;
  const int* tokens = side ? tokens2 : tokens1;
  int t0 = blockIdx.x * 2;
  if (threadIdx.x < 128) {
    int tl = threadIdx.x >> 6, j = threadIdx.x & 63;
    tok[tl][j] = tokens[(t0 + tl) * 64 + j];
  }
  __syncthreads();
  int tl = threadIdx.x >> 7;
  int c  = threadIdx.x & 127;
  float s[64];
#pragma unroll
  for (int j = 0; j < 64; ++j)
    s[j] = __uint_as_float(((unsigned)projb[(size_t)tok[tl][j] * 128 + c]) << 16);
  s[31] += s[63];
#pragma unroll
  for (int j = 30; j >= 0; --j) s[j] += s[2 * j + 1] + s[2 * j + 2];
  float m = s[0];
#pragma unroll
  for (int j = 1; j < 64; ++j) m = fmaxf(m, s[j]);
  m = fmaxf(m, 0.0f);
  seq[(size_t)(side * TPS + t0 + tl) * 128 + c] = m;
}

// ---- K3: gi[side][dir][b][s][r] = b_ih[r] + sum_k seq[side][t][k]*w_ih[r][k]
__global__ __launch_bounds__(256) void k_gi(const float* __restrict__ seq,
                                            const float* __restrict__ wihT_f,
                                            const float* __restrict__ wihT_b,
                                            const float* __restrict__ b_ih_f,
                                            const float* __restrict__ b_ih_b,
                                            float* __restrict__ gi) {
  __shared__ float wT[128 * 128];   // [k][r-chunk]
  __shared__ float sq[16][128];
  int ttile = blockIdx.x;           // 0..127
  int rc = blockIdx.y;              // 0..2
  int sd = blockIdx.z;              // side*2+dir
  int side = sd >> 1, dir = sd & 1;
  const float* wihT = dir ? wihT_b : wihT_f;
  const float* b_ih = dir ? b_ih_b : b_ih_f;
  for (int idx = threadIdx.x; idx < 128 * 32; idx += 256) {
    int k = idx >> 5, r4 = idx & 31;
    ((float4*)wT)[idx] = *(const float4*)&wihT[k * G3 + rc * 128 + (r4 << 2)];
  }
  int t0 = ttile * 16;
  const float4* sqsrc = (const float4*)&seq[(size_t)(side * TPS + t0) * 128];
  for (int idx = threadIdx.x; idx < 16 * 32; idx += 256)
    ((float4*)sq)[idx] = sqsrc[idx];
  __syncthreads();
  int tt = threadIdx.x >> 5;        // t-pair 0..7
  int te = (threadIdx.x & 31) << 2; // r base
  float4 b4 = *(const float4*)&b_ih[rc * 128 + te];
  float4 a0 = b4, a1 = b4;
#pragma unroll 4
  for (int kk = 0; kk < 128; ++kk) {
    float4 w4 = *(float4*)&wT[kk * 128 + te];
    float e0 = sq[tt * 2 + 0][kk], e1 = sq[tt * 2 + 1][kk];
    a0.x = fmaf(e0, w4.x, a0.x); a0.y = fmaf(e0, w4.y, a0.y);
    a0.z = fmaf(e0, w4.z, a0.z); a0.w = fmaf(e0, w4.w, a0.w);
    a1.x = fmaf(e1, w4.x, a1.x); a1.y = fmaf(e1, w4.y, a1.y);
    a1.z = fmaf(e1, w4.z, a1.z); a1.w = fmaf(e1, w4.w, a1.w);
  }
#pragma unroll
  for (int i = 0; i < 2; ++i) {
    int t = t0 + tt * 2 + i;
    int b = t >> 5, s = t & 31;
    float4 v = i ? a1 : a0;
    *(float4*)&gi[((size_t)(sd * 64 + b) * 32 + s) * G3 + rc * 128 + te] = v;
  }
}

// ---- K4: GRU scans via MFMA. W_hh fragments staged ONCE into LDS (98KB,
//      the fast pipe: 12 ds_read_b128/wave/step vs rounds 2-10's 196KB/step
//      L2 re-stream = the 3400-cyc wall). gi precomputed, 1-step register
//      prefetch. h dbuf in LDS, 1 barrier/step.
#define KT 1040     // bytes per h ktile (64 lanes * 16B + 16B pad)
#define MM(dst, A, B) dst = __builtin_amdgcn_mfma_f32_16x16x32_bf16(A, B, dst, 0, 0, 0)

__global__ __launch_bounds__(512) void k_scan(
    const float* __restrict__ gi,
    const uint4* __restrict__ fragimg,
    const float* __restrict__ b_hh_f, const float* __restrict__ b_hh_b,
    float* __restrict__ hfin) {
  __shared__ __align__(16) uint4 wlds[6144];        // 98304 B: W_hh frags
  __shared__ __align__(16) unsigned hbuf[2][1040];  // 2 x 4160 B h B-frag dbuf
  int bx = blockIdx.x;
  int sd = bx & 3, pg = bx >> 2;
  int dir = sd & 1;
  const float* bhh = dir ? b_hh_b : b_hh_f;
  int tid = threadIdx.x;
  int w = tid >> 6, l = tid & 63;
  int p  = l & 15;          // program (B n / D col)
  int kb = l >> 4;          // k-block within fragment
  int c0 = 16 * w + 4 * kb; // D-row base

  // stage W_hh fragments (mat=1 section of fragimg) -> LDS
  for (int i = tid; i < 6144; i += 512) {
    int w_ = i / 768, r = i - w_ * 768;
    wlds[i] = fragimg[(size_t)(dir * 8 + w_) * 1536 + 768 + r];
  }
  for (int i = tid; i < 2080; i += 512) ((unsigned*)hbuf)[i] = 0u;

  f32x4 bhr = *(const f32x4*)&bhh[c0];
  f32x4 bhz = *(const f32x4*)&bhh[128 + c0];
  f32x4 bhn = *(const f32x4*)&bhh[256 + c0];

  const float* gbase = gi + (size_t)(sd * 64 + pg * 16 + p) * (32 * G3);
  int hwb = (c0 >> 5) * KT + (p + 16 * ((c0 & 31) >> 3)) * 16 + (c0 & 7) * 2;
  const uint4* wbase = wlds + w * 768 + l;   // + (g*4+t)*64

  float hc[4] = {0.f, 0.f, 0.f, 0.f};
  f32x4 z4 = {0.f, 0.f, 0.f, 0.f};
  __syncthreads();

  f32x4 gv[3], gn[3] = {z4, z4, z4};
  {
    int o = (dir ? 31 : 0) * G3;
#pragma unroll
    for (int g = 0; g < 3; ++g) gv[g] = *(const f32x4*)&gbase[o + g * 128 + c0];
  }

  for (int i = 0; i < 32; ++i) {
    // prefetch next step's gi (global, consumed next iter)
    if (i < 31) {
      int o = (dir ? (30 - i) : (i + 1)) * G3;
#pragma unroll
      for (int g = 0; g < 3; ++g) gn[g] = *(const f32x4*)&gbase[o + g * 128 + c0];
    }
    // h B-fragments from LDS
    const char* hb = (const char*)hbuf + (i & 1) * 4160;
    s16x8 bf[4];
#pragma unroll
    for (int t = 0; t < 4; ++t) {
      U8 u; u.u = *(const uint4*)(hb + t * KT + l * 16);
      bf[t] = u.s;
    }
    // W_hh from LDS + 12 MFMA (2 chains per gate), acc bias-initialized
    f32x4 aR0 = bhr, aR1 = z4, aZ0 = bhz, aZ1 = z4, aN0 = bhn, aN1 = z4;
#pragma unroll
    for (int t = 0; t < 4; ++t) {
      U8 u0, u1, u2;
      u0.u = wbase[(0 * 4 + t) * 64];
      u1.u = wbase[(1 * 4 + t) * 64];
      u2.u = wbase[(2 * 4 + t) * 64];
      if (t & 1) { MM(aR1, u0.s, bf[t]); MM(aZ1, u1.s, bf[t]); MM(aN1, u2.s, bf[t]); }
      else       { MM(aR0, u0.s, bf[t]); MM(aZ0, u1.s, bf[t]); MM(aN0, u2.s, bf[t]); }
    }
#pragma unroll
    for (int r4 = 0; r4 < 4; ++r4) {
      float rv = sigm(gv[0][r4] + aR0[r4] + aR1[r4]);
      float zv = sigm(gv[1][r4] + aZ0[r4] + aZ1[r4]);
      float nv = tanh_fast(gv[2][r4] + rv * (aN0[r4] + aN1[r4]));
      hc[r4] = (1.0f - zv) * nv + zv * hc[r4];
    }
    uint2 hp;
    hp.x = bf16_rn(hc[0]) | (bf16_rn(hc[1]) << 16);
    hp.y = bf16_rn(hc[2]) | (bf16_rn(hc[3]) << 16);
    *(uint2*)((char*)hbuf + ((i + 1) & 1) * 4160 + hwb) = hp;
    __syncthreads();
#pragma unroll
    for (int g = 0; g < 3; ++g) gv[g] = gn[g];
  }
  int scan = sd * 64 + pg * 16 + p;
#pragma unroll
  for (int r4 = 0; r4 < 4; ++r4)
    hfin[(size_t)scan * 128 + c0 + r4] = hc[r4];
}

// ---- K5: out[b] = sigmoid(|lvec-rvec| . w_out + b_out)
__global__ __launch_bounds__(64) void k_out(const float* __restrict__ hfin,
                                            const float* __restrict__ w_out,
                                            const float* __restrict__ b_out,
                                            float* __restrict__ out) {
  int b = blockIdx.x, lane = threadIdx.x;
  float p = 0.f;
#pragma unroll
  for (int i = 0; i < 2; ++i) {
    int c = lane + i * 64;
    float l = hfin[(size_t)(0   + b) * 128 + c] + hfin[(size_t)(64  + b) * 128 + c];
    float r = hfin[(size_t)(128 + b) * 128 + c] + hfin[(size_t)(192 + b) * 128 + c];
    p += fabsf(l - r) * w_out[c];
  }
#pragma unroll
  for (int off = 32; off > 0; off >>= 1) p += __shfl_down(p, off);
  if (lane == 0) out[b] = sigm(p + b_out[0]);
}

extern "C" void kernel_launch(void* const* d_in, const int* in_sizes, int n_in,
                              void* d_out, int out_size, void* d_ws, size_t ws_size,
                              hipStream_t stream) {
  (void)in_sizes; (void)n_in; (void)out_size; (void)ws_size;
  const int*   tokens1 = (const int*)d_in[0];
  const int*   tokens2 = (const int*)d_in[2];
  const float* emb     = (const float*)d_in[4];
  const float* w_c     = (const float*)d_in[5];
  const float* b_c     = (const float*)d_in[6];
  const float* w_ih_f  = (const float*)d_in[7];
  const float* w_hh_f  = (const float*)d_in[8];
  const float* b_ih_f  = (const float*)d_in[9];
  const float* b_hh_f  = (const float*)d_in[10];
  const float* w_ih_b  = (const float*)d_in[11];
  const float* w_hh_b  = (const float*)d_in[12];
  const float* b_ih_b  = (const float*)d_in[13];
  const float* b_hh_b  = (const float*)d_in[14];
  const float* w_out   = (const float*)d_in[15];
  const float* b_out   = (const float*)d_in[16];
  float* ws = (float*)d_ws;
  unsigned short* projb = (unsigned short*)(ws + OFF_PROJ);
  float* wcT    = ws + OFF_WCT;
  float* wihT_f = ws + OFF_WIHTF;
  float* wihT_b = ws + OFF_WIHTB;
  float* seq    = ws + OFF_SEQ;
  float* gi     = ws + OFF_GI;
  float* hfin   = ws + OFF_HFIN;
  uint4* fragimg = (uint4*)(ws + OFF_FRAG);

  k_transpose3<<<28, 256, 0, stream>>>(w_c, w_ih_f, w_ih_b, wcT, wihT_f, wihT_b);
  k_pack<<<96, 256, 0, stream>>>(w_ih_f, w_ih_b, w_hh_f, w_hh_b, fragimg);
  k_proj<<<(VSZ + 31) / 32, 256, 0, stream>>>(emb, wcT, b_c, projb);
  k_tree<<<dim3(TPS / 2, 2), 256, 0, stream>>>(tokens1, tokens2, projb, seq);
  k_gi<<<dim3(128, 3, 4), 256, 0, stream>>>(seq, wihT_f, wihT_b, b_ih_f, b_ih_b, gi);
  k_scan<<<16, 512, 0, stream>>>(gi, fragimg, b_hh_f, b_hh_b, hfin);
  k_out<<<64, 64, 0, stream>>>(hfin, w_out, b_out, (float*)d_out);
}

// Round 12
// 95.850 us; speedup vs baseline: 1.4491x; 1.4491x over previous
//
#include <hip/hip_runtime.h>
#include <stdint.h>

#define VSZ 30000
#define TPS 2048      // trees per side
#define G3  384

// workspace layout (float offsets)
#define OFF_PROJ   0u          // 30000*128 bf16 = 1,920,000 floats
#define OFF_SEQ    1920000u    // 2*2048*128
#define OFF_HFIN   2444288u    // 256*128
#define OFF_FRAG   2477056u    // 24576 uint4 = 98304 floats

using f32x4 = __attribute__((ext_vector_type(4))) float;
using s16x8 = __attribute__((ext_vector_type(8))) short;
union U8 { uint4 u; s16x8 s; };

__device__ __forceinline__ float sigm(float x) { return 1.0f / (1.0f + __expf(-x)); }
__device__ __forceinline__ float tanh_fast(float x) {
  float e = __expf(-2.0f * x);
  return 2.0f / (1.0f + e) - 1.0f;   // safe at both tails (no inf/inf)
}
__device__ __forceinline__ unsigned bf16_rn(float f) {
  unsigned u = __float_as_uint(f);
  return (u + 0x7FFFu + ((u >> 16) & 1u)) >> 16;   // round-to-nearest-even
}

#define KT 1040     // bytes per ktile (64 lanes * 16B + 16B pad)
#define XS 4160     // bytes per 16-row B-tile (4 ktiles)
#define MM(dst, A, B) dst = __builtin_amdgcn_mfma_f32_16x16x32_bf16(A, B, dst, 0, 0, 0)

// ---- K0: pre-pack GRU weight MFMA A-fragments as bf16, one dwordx4/lane.
//      idx = ((((dir*8+w)*2+mat)*3+g)*4+t)*64 + l   (mat0=W_ih, mat1=W_hh)
__global__ __launch_bounds__(256) void k_pack(
    const float* __restrict__ w_ih_f, const float* __restrict__ w_ih_b,
    const float* __restrict__ w_hh_f, const float* __restrict__ w_hh_b,
    uint4* __restrict__ fragimg) {
  int idx = blockIdx.x * 256 + threadIdx.x;    // 0..24575
  int l = idx & 63;
  int t = (idx >> 6) & 3;
  int r = idx >> 8;
  int g = r % 3; r /= 3;
  int mat = r & 1; r >>= 1;
  int w = r & 7;
  int dir = r >> 3;
  const float* src = mat ? (dir ? w_hh_b : w_hh_f) : (dir ? w_ih_b : w_ih_f);
  int row = g * 128 + 16 * w + (l & 15);
  int ks  = t * 32 + (l >> 4) * 8;
  float4 f0 = *(const float4*)&src[row * 128 + ks];
  float4 f1 = *(const float4*)&src[row * 128 + ks + 4];
  uint4 u;
  u.x = bf16_rn(f0.x) | (bf16_rn(f0.y) << 16);
  u.y = bf16_rn(f0.z) | (bf16_rn(f0.w) << 16);
  u.z = bf16_rn(f1.x) | (bf16_rn(f1.y) << 16);
  u.w = bf16_rn(f1.z) | (bf16_rn(f1.w) << 16);
  fragimg[idx] = u;
}

// ---- K1: MFMA vocab projection. proj[v][eo] = b_c[eo] + emb[v][:].w_c[eo][:]
//      A = w_c (m=eo; 4 persistent frags/wave), B = emb 16-row tiles staged
//      bf16 in LDS (k_scan's verified B-frag staging pattern). D: col=v,
//      row=eo -> 4 contiguous eo per lane = packed uint2 store.
__global__ __launch_bounds__(512) void k_proj(const float* __restrict__ emb,
                                              const float* __restrict__ w_c,
                                              const float* __restrict__ b_c,
                                              unsigned short* __restrict__ projb) {
  __shared__ __align__(16) char blds[8 * XS];   // 33280 B
  int tid = threadIdx.x;
  int v0 = blockIdx.x * 128;
  // stage 128 emb rows as 8 B-frag tiles (16 rows each)
  {
    int pp = tid >> 5, cc = tid & 31;
    int wbyte = (cc >> 3) * KT + (pp + 16 * ((cc & 7) >> 1)) * 16 + (cc & 1) * 8;
    for (int nt = 0; nt < 8; ++nt) {
      int row = v0 + nt * 16 + pp;
      float4 v = make_float4(0.f, 0.f, 0.f, 0.f);
      if (row < VSZ) v = *(const float4*)&emb[(size_t)row * 128 + 4 * cc];
      uint2 u;
      u.x = bf16_rn(v.x) | (bf16_rn(v.y) << 16);
      u.y = bf16_rn(v.z) | (bf16_rn(v.w) << 16);
      *(uint2*)(blds + nt * XS + wbyte) = u;
    }
  }
  int w = tid >> 6, l = tid & 63;
  // A-frags: w_c rows 16w + (l&15), k = t*32 + (l>>4)*8 + j
  s16x8 af[4];
  {
    int row = 16 * w + (l & 15);
    int kb = (l >> 4) * 8;
#pragma unroll
    for (int t = 0; t < 4; ++t) {
      float4 f0 = *(const float4*)&w_c[row * 128 + t * 32 + kb];
      float4 f1 = *(const float4*)&w_c[row * 128 + t * 32 + kb + 4];
      U8 u;
      u.u.x = bf16_rn(f0.x) | (bf16_rn(f0.y) << 16);
      u.u.y = bf16_rn(f0.z) | (bf16_rn(f0.w) << 16);
      u.u.z = bf16_rn(f1.x) | (bf16_rn(f1.y) << 16);
      u.u.w = bf16_rn(f1.z) | (bf16_rn(f1.w) << 16);
      af[t] = u.s;
    }
  }
  f32x4 bias = *(const f32x4*)&b_c[16 * w + (l >> 4) * 4];
  __syncthreads();
  for (int nt = 0; nt < 8; ++nt) {
    s16x8 bf[4];
#pragma unroll
    for (int t = 0; t < 4; ++t) {
      U8 u; u.u = *(const uint4*)(blds + nt * XS + t * KT + l * 16);
      bf[t] = u.s;
    }
    f32x4 acc = bias;
    MM(acc, af[0], bf[0]); MM(acc, af[1], bf[1]);
    MM(acc, af[2], bf[2]); MM(acc, af[3], bf[3]);
    int v = v0 + nt * 16 + (l & 15);
    if (v < VSZ) {
      uint2 u;
      u.x = bf16_rn(acc[0]) | (bf16_rn(acc[1]) << 16);
      u.y = bf16_rn(acc[2]) | (bf16_rn(acc[3]) << 16);
      *(uint2*)&projb[(size_t)v * 128 + 16 * w + (l >> 4) * 4] = u;
    }
  }
}

// ---- K2: per-tree subtree sums (heap), coord-wise max, ReLU -> seq[side][t][c]
__global__ __launch_bounds__(512) void k_tree(const int* __restrict__ tokens1,
                                              const int* __restrict__ tokens2,
                                              const unsigned short* __restrict__ projb,
                                              float* __restrict__ seq) {
  __shared__ int tok[4][64];
  int side = blockIdx.y;
  const int* tokens = side ? tokens2 : tokens1;
  int t0 = blockIdx.x * 4;
  if (threadIdx.x < 256) {
    int tl = threadIdx.x >> 6, j = threadIdx.x & 63;
    tok[tl][j] = tokens[(t0 + tl) * 64 + j];
  }
  __syncthreads();
  int tl = threadIdx.x >> 7;
  int c  = threadIdx.x & 127;
  float s[64];
#pragma unroll
  for (int j = 0; j < 64; ++j)
    s[j] = __uint_as_float(((unsigned)projb[(size_t)tok[tl][j] * 128 + c]) << 16);
  s[31] += s[63];
#pragma unroll
  for (int j = 30; j >= 0; --j) s[j] += s[2 * j + 1] + s[2 * j + 2];
  float m = s[0];
#pragma unroll
  for (int j = 1; j < 64; ++j) m = fmaxf(m, s[j]);
  m = fmaxf(m, 0.0f);
  seq[(size_t)(side * TPS + t0 + tl) * 128 + c] = m;
}

// ---- K3: fused GRU scans via MFMA (round-10 form, best total). x staged
//      bf16 in LDS; weight fragments = single dwordx4 loads from fragimg
//      (worst-case allocator behavior = cheap L2 reloads, no convert DAG).
__global__ __launch_bounds__(512) void k_scan(
    const float* __restrict__ seq,
    const uint4* __restrict__ fragimg,
    const float* __restrict__ b_ih_f, const float* __restrict__ b_ih_b,
    const float* __restrict__ b_hh_f, const float* __restrict__ b_hh_b,
    float* __restrict__ hfin) {
  __shared__ __align__(16) unsigned lds[35360];   // 141440 B: 32 x-tiles + 2 h-tiles
  int bx = blockIdx.x;
  int sd = bx & 3, pg = bx >> 2;
  int side = sd >> 1, dir = sd & 1;
  const float* bih = dir ? b_ih_b : b_ih_f;
  const float* bhh = dir ? b_hh_b : b_hh_f;
  int tid = threadIdx.x;
  int w = tid >> 6, l = tid & 63;
  int p  = l & 15;          // program (B n / D col)
  int kb = l >> 4;          // k-block within fragment
  int c0 = 16 * w + 4 * kb; // D-row base

  // --- stage x -> LDS bf16 B-frag tiles (by sequence position)
  {
    int pp = tid >> 5, cc = tid & 31;
    int wbyte = (cc >> 3) * KT + (pp + 16 * ((cc & 7) >> 1)) * 16 + (cc & 1) * 8;
    const float* srow = seq + (size_t)(side * TPS + (pg * 16 + pp) * 32) * 128 + 4 * cc;
    for (int ss = 0; ss < 32; ++ss) {
      float4 v = *(const float4*)(srow + (size_t)ss * 128);
      uint2 u;
      u.x = bf16_rn(v.x) | (bf16_rn(v.y) << 16);
      u.y = bf16_rn(v.z) | (bf16_rn(v.w) << 16);
      *(uint2*)((char*)lds + ss * XS + wbyte) = u;
    }
  }
  for (int i = tid; i < 2080; i += 512) lds[32 * 1040 + i] = 0u;

  // --- persistent A-fragments: single 16B load each from fragimg
  const uint4* fbase = fragimg + (size_t)(dir * 8 + w) * 1536 + l;
  s16x8 ai[3][4], ah[3][4];
#pragma unroll
  for (int g = 0; g < 3; ++g)
#pragma unroll
    for (int t = 0; t < 4; ++t) {
      U8 u;
      u.u = fbase[g * 256 + t * 64];        ai[g][t] = u.s;   // W_ih
      u.u = fbase[768 + g * 256 + t * 64];  ah[g][t] = u.s;   // W_hh
    }

  f32x4 bir = *(const f32x4*)&bih[c0],       bhr = *(const f32x4*)&bhh[c0];
  f32x4 biz = *(const f32x4*)&bih[128 + c0], bhz = *(const f32x4*)&bhh[128 + c0];
  f32x4 bin = *(const f32x4*)&bih[256 + c0], bhn = *(const f32x4*)&bhh[256 + c0];
  f32x4 bbr = bir + bhr, bbz = biz + bhz;

  int hwb = (c0 >> 5) * KT + (p + 16 * ((c0 & 31) >> 3)) * 16 + (c0 & 7) * 2;

  float hc[4] = {0.f, 0.f, 0.f, 0.f};
  f32x4 z4 = {0.f, 0.f, 0.f, 0.f};
  __syncthreads();

  for (int i = 0; i < 32; ++i) {
    int pos = dir ? (31 - i) : i;
    const char* xb = (const char*)lds + pos * XS;
    const char* hb = (const char*)lds + (32 + (i & 1)) * XS;
    s16x8 xf[4], bf[4];
#pragma unroll
    for (int t = 0; t < 4; ++t) {
      U8 ux; ux.u = *(const uint4*)(xb + t * KT + l * 16); xf[t] = ux.s;
      U8 uh; uh.u = *(const uint4*)(hb + t * KT + l * 16); bf[t] = uh.s;
    }
    f32x4 aR0 = bbr, aR1 = z4, aZ0 = bbz, aZ1 = z4;
    f32x4 aNi0 = bin, aNi1 = z4, aNh0 = bhn, aNh1 = z4;
    MM(aR0,  ai[0][0], xf[0]); MM(aZ0,  ai[1][0], xf[0]); MM(aNi0, ai[2][0], xf[0]);
    MM(aR1,  ai[0][1], xf[1]); MM(aZ1,  ai[1][1], xf[1]); MM(aNi1, ai[2][1], xf[1]);
    MM(aR0,  ai[0][2], xf[2]); MM(aZ0,  ai[1][2], xf[2]); MM(aNi0, ai[2][2], xf[2]);
    MM(aR1,  ai[0][3], xf[3]); MM(aZ1,  ai[1][3], xf[3]); MM(aNi1, ai[2][3], xf[3]);
    MM(aNh0, ah[2][0], bf[0]); MM(aR0,  ah[0][0], bf[0]); MM(aZ0,  ah[1][0], bf[0]);
    MM(aNh1, ah[2][1], bf[1]); MM(aR1,  ah[0][1], bf[1]); MM(aZ1,  ah[1][1], bf[1]);
    MM(aNh0, ah[2][2], bf[2]); MM(aR0,  ah[0][2], bf[2]); MM(aZ0,  ah[1][2], bf[2]);
    MM(aNh1, ah[2][3], bf[3]); MM(aR1,  ah[0][3], bf[3]); MM(aZ1,  ah[1][3], bf[3]);
#pragma unroll
    for (int r4 = 0; r4 < 4; ++r4) {
      float rv = sigm(aR0[r4] + aR1[r4]);
      float zv = sigm(aZ0[r4] + aZ1[r4]);
      float nv = tanh_fast(aNi0[r4] + aNi1[r4] + rv * (aNh0[r4] + aNh1[r4]));
      hc[r4] = (1.0f - zv) * nv + zv * hc[r4];
    }
    uint2 hp;
    hp.x = bf16_rn(hc[0]) | (bf16_rn(hc[1]) << 16);
    hp.y = bf16_rn(hc[2]) | (bf16_rn(hc[3]) << 16);
    *(uint2*)((char*)lds + (32 + ((i + 1) & 1)) * XS + hwb) = hp;
    __syncthreads();
  }
  int scan = sd * 64 + pg * 16 + p;
#pragma unroll
  for (int r4 = 0; r4 < 4; ++r4)
    hfin[(size_t)scan * 128 + c0 + r4] = hc[r4];
}

// ---- K4: out[b] = sigmoid(|lvec-rvec| . w_out + b_out)
__global__ __launch_bounds__(64) void k_out(const float* __restrict__ hfin,
                                            const float* __restrict__ w_out,
                                            const float* __restrict__ b_out,
                                            float* __restrict__ out) {
  int b = blockIdx.x, lane = threadIdx.x;
  float p = 0.f;
#pragma unroll
  for (int i = 0; i < 2; ++i) {
    int c = lane + i * 64;
    float l = hfin[(size_t)(0   + b) * 128 + c] + hfin[(size_t)(64  + b) * 128 + c];
    float r = hfin[(size_t)(128 + b) * 128 + c] + hfin[(size_t)(192 + b) * 128 + c];
    p += fabsf(l - r) * w_out[c];
  }
#pragma unroll
  for (int off = 32; off > 0; off >>= 1) p += __shfl_down(p, off);
  if (lane == 0) out[b] = sigm(p + b_out[0]);
}

extern "C" void kernel_launch(void* const* d_in, const int* in_sizes, int n_in,
                              void* d_out, int out_size, void* d_ws, size_t ws_size,
                              hipStream_t stream) {
  (void)in_sizes; (void)n_in; (void)out_size; (void)ws_size;
  const int*   tokens1 = (const int*)d_in[0];
  const int*   tokens2 = (const int*)d_in[2];
  const float* emb     = (const float*)d_in[4];
  const float* w_c     = (const float*)d_in[5];
  const float* b_c     = (const float*)d_in[6];
  const float* w_ih_f  = (const float*)d_in[7];
  const float* w_hh_f  = (const float*)d_in[8];
  const float* b_ih_f  = (const float*)d_in[9];
  const float* b_hh_f  = (const float*)d_in[10];
  const float* w_ih_b  = (const float*)d_in[11];
  const float* w_hh_b  = (const float*)d_in[12];
  const float* b_ih_b  = (const float*)d_in[13];
  const float* b_hh_b  = (const float*)d_in[14];
  const float* w_out   = (const float*)d_in[15];
  const float* b_out   = (const float*)d_in[16];
  float* ws = (float*)d_ws;
  unsigned short* projb = (unsigned short*)(ws + OFF_PROJ);
  float* seq    = ws + OFF_SEQ;
  float* hfin   = ws + OFF_HFIN;
  uint4* fragimg = (uint4*)(ws + OFF_FRAG);

  k_pack<<<96, 256, 0, stream>>>(w_ih_f, w_ih_b, w_hh_f, w_hh_b, fragimg);
  k_proj<<<(VSZ + 127) / 128, 512, 0, stream>>>(emb, w_c, b_c, projb);
  k_tree<<<dim3(TPS / 4, 2), 512, 0, stream>>>(tokens1, tokens2, projb, seq);
  k_scan<<<16, 512, 0, stream>>>(seq, fragimg, b_ih_f, b_ih_b, b_hh_f, b_hh_b, hfin);
  k_out<<<64, 64, 0, stream>>>(hfin, w_out, b_out, (float*)d_out);
}